// Round 3
// baseline (82.221 us; speedup 1.0000x reference)
//
#include <hip/hip_runtime.h>

// ---------------------------------------------------------------------------
// Stacked 3-layer LSTM step + projection, B=256, I=512, H=1024, V=512 (fp32 io)
// bf16 MFMA GEMMs: BN=64 col strips x K-split-4 -> 256 blocks (1/CU, 8 waves),
// 4-deep register prefetch pipeline (issue->stage distance = 3 barriers).
// ---------------------------------------------------------------------------

typedef __attribute__((ext_vector_type(8))) short short8_t;            // 8 bf16 (MFMA frag)
typedef __attribute__((ext_vector_type(8))) unsigned short ushort8_t;  // 16B ld/st
typedef __attribute__((ext_vector_type(4))) unsigned short ushort4_t;  // 8B st
typedef __attribute__((ext_vector_type(4))) float f32x4;               // MFMA acc / 16B ld

__device__ __forceinline__ unsigned short f2bf(float f) {
    union { float f; unsigned u; } v; v.f = f;
    unsigned r = v.u + 0x7FFFu + ((v.u >> 16) & 1u);   // RTNE (finite inputs)
    return (unsigned short)(r >> 16);
}

#define KT 64
#define BN 64

// ---------------------------------------------------------------------------
// zp[kb][256][N] = A[256][K-slice kb] @ W[K-slice kb][N]
// A = concat(A1[256][K1], A2[256][Ktot-K1]) bf16; W rows fp32 -> bf16 in reg.
// Block: 512 thr (8 waves), BM=256 (full M), BN=64 cols, K-slice = Ktot>>lgs.
// grid = (N/64) << lgs. Wave w: rows [w*32, w*32+32) x all 64 cols
//   -> 2 m-subtiles x 4 n-tiles = 8 acc frags, 16 MFMA / K-tile.
// ---------------------------------------------------------------------------
__global__ __launch_bounds__(512, 1)
void gemm64(const unsigned short* __restrict__ A1, const float* __restrict__ W1, int K1,
            const unsigned short* __restrict__ A2, const float* __restrict__ W2,
            int N, int Ktot, int lgs, float* __restrict__ zp)
{
    __shared__ unsigned short Al[2][256 * KT];   // 2 x 32 KB, 16B-chunk XOR swizzle
    __shared__ unsigned short Wl[2][BN * KT];    // 2 x 8 KB, [n][k] transposed, swizzled

    const int tid  = threadIdx.x;
    const int lane = tid & 63;
    const int w    = tid >> 6;
    const int lg   = lane >> 4;
    const int lr   = lane & 15;
    const int nsplit = 1 << lgs;
    const int kb   = blockIdx.x & (nsplit - 1);
    const int ns   = blockIdx.x >> lgs;
    const int n0   = ns * BN;
    const int m0   = w * 32;
    const int klen = Ktot >> lgs;
    const int kbeg = kb * klen;
    const int nt   = klen >> 6;

    const int wr = tid >> 3;               // W k-row within tile (0..63)
    const int wq = tid & 7;                // W quad base (0..7)

    // 4 prefetch register sets (static names - rule #20)
    ushort8_t pa0[4], pa1[4], pa2[4], pa3[4];
    f32x4     pw0[2], pw1[2], pw2[2], pw3[2];

    f32x4 acc[2][4];
#pragma unroll
    for (int i = 0; i < 2; ++i)
#pragma unroll
        for (int j = 0; j < 4; ++j) acc[i][j] = f32x4{0.f, 0.f, 0.f, 0.f};

    auto issue = [&](int t, ushort8_t (&pa)[4], f32x4 (&pw)[2]) {
        int k0 = kbeg + t * KT;
        const unsigned short* A; const float* Wm; int ldA, krel;
        if (k0 < K1) { A = A1; Wm = W1; ldA = K1;        krel = k0; }
        else         { A = A2; Wm = W2; ldA = Ktot - K1; krel = k0 - K1; }
#pragma unroll
        for (int it = 0; it < 4; ++it) {
            int c = tid + it * 512;        // 2048 chunks = 256 rows x 8
            int row = c >> 3, cc = c & 7;
            pa[it] = *(const ushort8_t*)(A + (size_t)row * ldA + krel + cc * 8);
        }
        const float* wrow = Wm + (size_t)(krel + wr) * N + n0;
        pw[0] = *(const f32x4*)(wrow + wq * 4);
        pw[1] = *(const f32x4*)(wrow + (wq + 8) * 4);
    };

    auto stage = [&](ushort8_t (&pa)[4], f32x4 (&pw)[2],
                     unsigned short* al, unsigned short* wl) {
#pragma unroll
        for (int it = 0; it < 4; ++it) {
            int c = tid + it * 512;
            int row = c >> 3, cc = c & 7;
            *(ushort8_t*)(al + row * KT + ((cc ^ (row & 7)) << 3)) = pa[it];
        }
        int kch = wr >> 3, kwi = wr & 7;
#pragma unroll
        for (int p = 0; p < 2; ++p) {
            int qq = wq + p * 8;
#pragma unroll
            for (int j = 0; j < 4; ++j) {
                int n = qq * 4 + j;        // transposed: Wl[n][k]
                wl[n * KT + ((kch ^ (n & 7)) << 3) + kwi] = f2bf(pw[p][j]);
            }
        }
    };

    auto compute = [&](const unsigned short* al, const unsigned short* wl) {
#pragma unroll
        for (int ks = 0; ks < 2; ++ks) {
            int ch = ks * 4 + lg;
            int r0 = m0 + lr, r1 = r0 + 16;
            short8_t a0 = *(const short8_t*)(al + r0 * KT + ((ch ^ (r0 & 7)) << 3));
            short8_t a1 = *(const short8_t*)(al + r1 * KT + ((ch ^ (r1 & 7)) << 3));
#pragma unroll
            for (int n4 = 0; n4 < 4; ++n4) {
                int nb = n4 * 16 + lr;
                short8_t b = *(const short8_t*)(wl + nb * KT + ((ch ^ (nb & 7)) << 3));
                acc[0][n4] = __builtin_amdgcn_mfma_f32_16x16x32_bf16(a0, b, acc[0][n4], 0, 0, 0);
                acc[1][n4] = __builtin_amdgcn_mfma_f32_16x16x32_bf16(a1, b, acc[1][n4], 0, 0, 0);
            }
        }
    };

    // prologue: 3 tiles in flight, tile 0 staged
    if (0 < nt) issue(0, pa0, pw0);
    if (1 < nt) issue(1, pa1, pw1);
    if (2 < nt) issue(2, pa2, pw2);
    stage(pa0, pw0, Al[0], Wl[0]);
    __syncthreads();

    for (int t = 0; t < nt; t += 4) {
        // phase 0: compute t (LDS0), stage t+1 -> LDS1, issue t+3 -> set3
        if (t + 3 < nt) issue(t + 3, pa3, pw3);
        if (t + 1 < nt) stage(pa1, pw1, Al[1], Wl[1]);
        compute(Al[0], Wl[0]);
        __syncthreads();
        // phase 1: compute t+1 (LDS1), stage t+2 -> LDS0, issue t+4 -> set0
        if (t + 4 < nt) issue(t + 4, pa0, pw0);
        if (t + 2 < nt) stage(pa2, pw2, Al[0], Wl[0]);
        if (t + 1 < nt) compute(Al[1], Wl[1]);
        __syncthreads();
        // phase 2
        if (t + 5 < nt) issue(t + 5, pa1, pw1);
        if (t + 3 < nt) stage(pa3, pw3, Al[1], Wl[1]);
        if (t + 2 < nt) compute(Al[0], Wl[0]);
        __syncthreads();
        // phase 3
        if (t + 6 < nt) issue(t + 6, pa2, pw2);
        if (t + 4 < nt) stage(pa0, pw0, Al[0], Wl[0]);
        if (t + 3 < nt) compute(Al[1], Wl[1]);
        __syncthreads();
    }

    // epilogue: D mapping col=lane&15, row=4*(lane>>4)+reg  [m89/m91]
    float* zq = zp + (size_t)kb * 256 * N;
#pragma unroll
    for (int ms = 0; ms < 2; ++ms)
#pragma unroll
        for (int n4 = 0; n4 < 4; ++n4)
#pragma unroll
            for (int r = 0; r < 4; ++r) {
                int row = m0 + ms * 16 + lg * 4 + r;
                zq[(size_t)row * N + n0 + n4 * 16 + lr] = acc[ms][n4][r];
            }
}

// ---------------------------------------------------------------------------
// Gates: z = sum_kb zp[kb] + bias -> h_new, c_new (fp32) + h_new bf16
// ---------------------------------------------------------------------------
__global__ __launch_bounds__(256)
void lstm_gates(const float* __restrict__ zp, int nsplit,
                const float* __restrict__ bias, const float* __restrict__ c_old,
                float* __restrict__ h_out, float* __restrict__ c_out,
                unsigned short* __restrict__ h_bf)
{
    int t = blockIdx.x * 256 + threadIdx.x;   // 65536 threads, 4 elems each
    int b = t >> 8;
    int n = (t & 255) << 2;
    f32x4 iv = *(const f32x4*)(bias + n);
    f32x4 fv = *(const f32x4*)(bias + 1024 + n);
    f32x4 gv = *(const f32x4*)(bias + 2048 + n);
    f32x4 ov = *(const f32x4*)(bias + 3072 + n);
    for (int kb = 0; kb < nsplit; ++kb) {
        const float* z = zp + (size_t)kb * 1048576 + (size_t)b * 4096;
        iv += *(const f32x4*)(z + n);
        fv += *(const f32x4*)(z + 1024 + n);
        gv += *(const f32x4*)(z + 2048 + n);
        ov += *(const f32x4*)(z + 3072 + n);
    }
    f32x4 cv = *(const f32x4*)(c_old + (size_t)b * 1024 + n);

    f32x4 hn, cn;
    ushort4_t hb;
#pragma unroll
    for (int j = 0; j < 4; ++j) {
        float ii = 1.f / (1.f + __expf(-iv[j]));
        float ff = 1.f / (1.f + __expf(-fv[j]));
        float gg = tanhf(gv[j]);
        float oo = 1.f / (1.f + __expf(-ov[j]));
        float c2 = ff * cv[j] + ii * gg;
        cn[j] = c2;
        float h2 = oo * tanhf(c2);
        hn[j] = h2;
        hb[j] = f2bf(h2);
    }
    *(f32x4*)(c_out + (size_t)b * 1024 + n) = cn;
    *(f32x4*)(h_out + (size_t)b * 1024 + n) = hn;
    *(ushort4_t*)(h_bf + (size_t)b * 1024 + n) = hb;
}

// ---------------------------------------------------------------------------
// logits = sum_kb zp[kb] + bp   (proj partial reduce), N=512
// ---------------------------------------------------------------------------
__global__ __launch_bounds__(256)
void finalize_proj(const float* __restrict__ zp, int nsplit,
                   const float* __restrict__ bp, float* __restrict__ logits)
{
    int t = blockIdx.x * 256 + threadIdx.x;   // 32768 threads x 4 elems
    int i = t * 4;
    f32x4 v = *(const f32x4*)(bp + (i & 511));
    for (int kb = 0; kb < nsplit; ++kb)
        v += *(const f32x4*)(zp + (size_t)kb * 131072 + i);
    *(f32x4*)(logits + i) = v;
}

// ---------------------------------------------------------------------------
// Pack fp32 -> bf16 for x, h0, h1, h2
// ---------------------------------------------------------------------------
__global__ __launch_bounds__(256)
void pack_bf16(const float* __restrict__ x,  const float* __restrict__ h0,
               const float* __restrict__ h1, const float* __restrict__ h2,
               unsigned short* __restrict__ xb,  unsigned short* __restrict__ h0b,
               unsigned short* __restrict__ h1b, unsigned short* __restrict__ h2b)
{
    int t = blockIdx.x * 256 + threadIdx.x;
    const float* src; unsigned short* dst; int off;
    if (t < 32768)       { src = x;  dst = xb;  off = t; }
    else if (t < 98304)  { src = h0; dst = h0b; off = t - 32768; }
    else if (t < 163840) { src = h1; dst = h1b; off = t - 98304; }
    else                 { src = h2; dst = h2b; off = t - 163840; }
    f32x4 v = *(const f32x4*)(src + (size_t)off * 4);
    ushort4_t o;
#pragma unroll
    for (int j = 0; j < 4; ++j) o[j] = f2bf(v[j]);
    *(ushort4_t*)(dst + (size_t)off * 4) = o;
}

// ---------------------------------------------------------------------------
extern "C" void kernel_launch(void* const* d_in, const int* in_sizes, int n_in,
                              void* d_out, int out_size, void* d_ws, size_t ws_size,
                              hipStream_t stream)
{
    const float* x  = (const float*)d_in[0];
    const float* h0 = (const float*)d_in[1];
    const float* c0 = (const float*)d_in[2];
    const float* h1 = (const float*)d_in[3];
    const float* c1 = (const float*)d_in[4];
    const float* h2 = (const float*)d_in[5];
    const float* c2 = (const float*)d_in[6];
    const float* W0 = (const float*)d_in[7];
    const float* U0 = (const float*)d_in[8];
    const float* b0 = (const float*)d_in[9];
    const float* W1 = (const float*)d_in[10];
    const float* U1 = (const float*)d_in[11];
    const float* b1 = (const float*)d_in[12];
    const float* W2 = (const float*)d_in[13];
    const float* U2 = (const float*)d_in[14];
    const float* b2 = (const float*)d_in[15];
    const float* Wp = (const float*)d_in[16];
    const float* bp = (const float*)d_in[17];

    float* out    = (float*)d_out;
    float* logits = out;                    // [256,512]
    float* h0n = out + 131072;              // [256,1024] each below
    float* c0n = h0n + 262144;
    float* h1n = c0n + 262144;
    float* c1n = h1n + 262144;
    float* h2n = c1n + 262144;
    float* c2n = h2n + 262144;

    // nsplit=4 needs: zp 16MB + xb 256KB + 6x h-bf16 512KB = 20,185,088 B
    const size_t need4 = 16777216ull + 262144ull + 6ull * 524288ull;
    const int nsplit = (ws_size >= need4) ? 4 : 2;
    const int lgs    = (nsplit == 4) ? 2 : 1;
    const size_t zbytes = (size_t)nsplit * 4194304ull;

    char* ws = (char*)d_ws;
    float*          zp   = (float*)ws;                         // [nsplit][256][4096]
    unsigned short* xb   = (unsigned short*)(ws + zbytes);
    unsigned short* h0b  = (unsigned short*)(ws + zbytes + 262144);
    unsigned short* h1b  = (unsigned short*)(ws + zbytes + 262144 + 524288);
    unsigned short* h2b  = (unsigned short*)(ws + zbytes + 262144 + 2*524288);
    unsigned short* h0nb = (unsigned short*)(ws + zbytes + 262144 + 3*524288);
    unsigned short* h1nb = (unsigned short*)(ws + zbytes + 262144 + 4*524288);
    unsigned short* h2nb = (unsigned short*)(ws + zbytes + 262144 + 5*524288);

    pack_bf16<<<896, 256, 0, stream>>>(x, h0, h1, h2, xb, h0b, h1b, h2b);

    // layer 0: z = x@W0 + h0@U0   (K1=512, Ktot=1536)
    gemm64<<<64 * nsplit, 512, 0, stream>>>(xb, W0, 512, h0b, U0, 4096, 1536, lgs, zp);
    lstm_gates<<<256, 256, 0, stream>>>(zp, nsplit, b0, c0, h0n, c0n, h0nb);

    // layer 1: z = h0n@W1 + h1@U1  (K1=1024, Ktot=2048)
    gemm64<<<64 * nsplit, 512, 0, stream>>>(h0nb, W1, 1024, h1b, U1, 4096, 2048, lgs, zp);
    lstm_gates<<<256, 256, 0, stream>>>(zp, nsplit, b1, c1, h1n, c1n, h1nb);

    // layer 2: z = h1n@W2 + h2@U2  (K1=1024, Ktot=2048)
    gemm64<<<64 * nsplit, 512, 0, stream>>>(h1nb, W2, 1024, h2b, U2, 4096, 2048, lgs, zp);
    lstm_gates<<<256, 256, 0, stream>>>(zp, nsplit, b2, c2, h2n, c2n, h2nb);

    // projection: logits = h2n@Wp + bp  (K=1024, N=512; reuses zp region)
    gemm64<<<8 * nsplit, 512, 0, stream>>>(h2nb, Wp, 1024,
                                           (const unsigned short*)nullptr,
                                           (const float*)nullptr, 512, 1024, lgs, zp);
    finalize_proj<<<128, 256, 0, stream>>>(zp, nsplit, bp, logits);
}